// Round 5
// baseline (578.195 us; speedup 1.0000x reference)
//
#include <hip/hip_runtime.h>
#include <hip/hip_bf16.h>
#include <math.h>

#define D_MODEL 256
#define D_STATE 16
#define D_INNER 512
#define DT_RANK 16
#define NB 4
#define NVAR 32
#define SEG 96
#define TOKENS (NB*NVAR*SEG)   /* 12288 */

typedef float f4 __attribute__((ext_vector_type(4)));

__device__ __forceinline__ float silu_f(float x) { return x / (1.0f + __expf(-x)); }

// ---------------------------------------------------------------------------
// NT GEMM v2: C[m,n] = sum_k A[m,k] * W[n,k].
// 256 thr = 4 waves; BM=32 (wave owns 8 rows); BN=256 or 128 (lane owns
// CPL=BN/64 cols).  A staged via global_load_lds into [32][16] LDS, read as
// wave-uniform ds_read_b128 (HW broadcast, no s_load stalls).  W reg-staged
// transposed into k-major LDS [16][BN+4] (pad 4 words: writes 2-way max,
// reads conflict-free, b128-aligned).  BK=16, both double-buffered.
// MODE 0 plain; MODE 2 rows (b,v,s)->(b,s,v); MODE 3 inverse.
// ---------------------------------------------------------------------------
template<int K, int BN, int MODE>
__global__ __launch_bounds__(256, 4)
void gemm_v2(const float* __restrict__ A, const float* __restrict__ W,
             float* __restrict__ C, int N)
{
    constexpr int NT  = K / 16;
    constexpr int CPL = BN / 64;          // cols per lane (4 or 2)
    constexpr int WS  = BN + 4;           // LDS row stride, multiple of 4
    typedef float wvec __attribute__((ext_vector_type(CPL)));
    __shared__ float wlds[2 * 16 * WS];
    __shared__ float alds[2 * 512];       // [buf][32 rows][16 k]

    const int tid  = threadIdx.x;
    const int lane = tid & 63;
    const int wid  = tid >> 6;
    const int m0 = blockIdx.x * 32;
    const int n0 = blockIdx.y * BN;
    const int s_col = tid >> 2;           // 0..63
    const int s_kc  = (tid & 3) << 2;     // 0,4,8,12

    const float* Ag = A + (size_t)m0 * K;
    const float* Wg = W + (size_t)n0 * K;

    float acc[8][CPL];
#pragma unroll
    for (int i = 0; i < 8; i++)
#pragma unroll
        for (int c = 0; c < CPL; c++) acc[i][c] = 0.0f;

    // ---- A DMA: waves 0,1; row = tid>>2, kc = (tid&3)*4; LDS linear ----
#define STAGE_A(dbuf, k0)                                                      \
    if (tid < 128) {                                                           \
        int arow = tid >> 2;                                                   \
        int akc  = (tid & 3) << 2;                                             \
        int abase = __builtin_amdgcn_readfirstlane(((dbuf) << 9) + ((tid >> 6) << 8)); \
        __builtin_amdgcn_global_load_lds(                                      \
            (const __attribute__((address_space(1))) void*)(Ag + (size_t)arow * K + (k0) + akc), \
            (__attribute__((address_space(3))) void*)(alds + abase), 16, 0, 0); \
    }

    f4 wreg[CPL];
    // prologue: tile 0
    STAGE_A(0, 0);
#pragma unroll
    for (int c = 0; c < CPL; c++)
        wreg[c] = *(const f4*)(Wg + (size_t)(c * 64 + s_col) * K + s_kc);
#pragma unroll
    for (int c = 0; c < CPL; c++)
#pragma unroll
        for (int e = 0; e < 4; e++)
            wlds[(s_kc + e) * WS + c * 64 + s_col] = wreg[c][e];
    __syncthreads();

    for (int t = 0; t < NT; t++) {
        const int k0 = t * 16;
        if (t + 1 < NT) {                 // issue next-tile loads early
            STAGE_A((t + 1) & 1, k0 + 16);
#pragma unroll
            for (int c = 0; c < CPL; c++)
                wreg[c] = *(const f4*)(Wg + (size_t)(c * 64 + s_col) * K + k0 + 16 + s_kc);
        }
        const float* Ab = alds + (t & 1) * 512;
        const float* Wb = wlds + (t & 1) * 16 * WS;
#pragma unroll
        for (int kq = 0; kq < 4; kq++) {
            f4 a4[8];
#pragma unroll
            for (int i = 0; i < 8; i++)   // uniform addr -> LDS broadcast
                a4[i] = *(const f4*)(Ab + (wid * 8 + i) * 16 + kq * 4);
#pragma unroll
            for (int ke = 0; ke < 4; ke++) {
                wvec wv = *(const wvec*)(Wb + (kq * 4 + ke) * WS + CPL * lane);
#pragma unroll
                for (int i = 0; i < 8; i++)
#pragma unroll
                    for (int c = 0; c < CPL; c++)
                        acc[i][c] = fmaf(a4[i][ke], wv[c], acc[i][c]);
            }
        }
        if (t + 1 < NT) {                 // write-late into other buffer
            float* nb = wlds + ((t + 1) & 1) * 16 * WS;
#pragma unroll
            for (int c = 0; c < CPL; c++)
#pragma unroll
                for (int e = 0; e < 4; e++)
                    nb[(s_kc + e) * WS + c * 64 + s_col] = wreg[c][e];
        }
        __syncthreads();
    }
#undef STAGE_A

#pragma unroll
    for (int i = 0; i < 8; i++) {
        int m = m0 + wid * 8 + i;
        int orow = m;
        if (MODE == 2) {                  // (b*32+v)*96+s -> (b*96+s)*32+v
            int b = m / 3072, rr = m % 3072;
            int v = rr / 96, s = rr % 96;
            orow = (b * 96 + s) * 32 + v;
        } else if (MODE == 3) {           // (b*96+s)*32+v -> (b*32+v)*96+s
            int b = m / 3072, rr = m % 3072;
            int s = rr / 32, v = rr % 32;
            orow = (b * 32 + v) * 96 + s;
        }
        wvec v;
#pragma unroll
        for (int c = 0; c < CPL; c++) v[c] = acc[i][c];
        *(wvec*)(C + (size_t)orow * N + n0 + CPL * lane) = v;
    }
}

// ---------------------------------------------------------------------------
// Small tiled NT GEMM (x_proj N=48, dt_proj K=16).
// MODE 0: plain.  MODE 1: softplus(acc + bias[n]).
// ---------------------------------------------------------------------------
template<int BM, int BN, int BK, int TM, int TN, int MODE>
__global__ __launch_bounds__(256)
void gemm_nt(const float* __restrict__ A, int lda,
             const float* __restrict__ W,
             float* __restrict__ C,
             const float* __restrict__ bias,
             int M, int N, int K)
{
    __shared__ float As[BK][BM + 4];
    __shared__ float Ws[BK][BN + 4];

    const int tid = threadIdx.x;
    const int tx  = tid % (BN / TN);
    const int ty  = tid / (BN / TN);
    const int m0  = blockIdx.x * BM;
    const int n0  = blockIdx.y * BN;

    float acc[TM][TN];
#pragma unroll
    for (int i = 0; i < TM; i++)
#pragma unroll
        for (int j = 0; j < TN; j++) acc[i][j] = 0.0f;

    constexpr int AF4 = (BM * BK) / 1024;
    constexpr int WF4 = (BN * BK) / 1024;
    constexpr int F4R = BK / 4;

    for (int k0 = 0; k0 < K; k0 += BK) {
#pragma unroll
        for (int c = 0; c < AF4; c++) {
            int idx = tid + c * 256;
            int row = idx / F4R;
            int kc  = (idx % F4R) * 4;
            float4 v = *(const float4*)(A + (size_t)(m0 + row) * lda + k0 + kc);
            As[kc + 0][row] = v.x;
            As[kc + 1][row] = v.y;
            As[kc + 2][row] = v.z;
            As[kc + 3][row] = v.w;
        }
#pragma unroll
        for (int c = 0; c < WF4; c++) {
            int idx = tid + c * 256;
            int row = idx / F4R;
            int kc  = (idx % F4R) * 4;
            float4 v;
            if (n0 + row < N) v = *(const float4*)(W + (size_t)(n0 + row) * K + k0 + kc);
            else              v = make_float4(0.f, 0.f, 0.f, 0.f);
            Ws[kc + 0][row] = v.x;
            Ws[kc + 1][row] = v.y;
            Ws[kc + 2][row] = v.z;
            Ws[kc + 3][row] = v.w;
        }
        __syncthreads();

#pragma unroll
        for (int kk = 0; kk < BK; kk++) {
            float a[TM], w[TN];
#pragma unroll
            for (int i = 0; i < TM; i++) a[i] = As[kk][ty * TM + i];
#pragma unroll
            for (int j = 0; j < TN; j++) w[j] = Ws[kk][tx * TN + j];
#pragma unroll
            for (int i = 0; i < TM; i++)
#pragma unroll
                for (int j = 0; j < TN; j++)
                    acc[i][j] = fmaf(a[i], w[j], acc[i][j]);
        }
        __syncthreads();
    }

#pragma unroll
    for (int i = 0; i < TM; i++) {
        int m = m0 + ty * TM + i;
#pragma unroll
        for (int j = 0; j < TN; j++) {
            int n = n0 + tx * TN + j;
            if (n < N) {
                float v = acc[i][j];
                if (MODE == 1) {
                    v += bias[n];
                    v = (v > 20.0f) ? v : log1pf(__expf(v));
                }
                C[(size_t)m * N + n] = v;
            }
        }
    }
}

// ---------------------------------------------------------------------------
// Depthwise causal conv (width 4) + bias + SiLU.
// ---------------------------------------------------------------------------
__global__ __launch_bounds__(256)
void conv_silu(const float* __restrict__ xz, const float* __restrict__ cw,
               const float* __restrict__ cb, float* __restrict__ xc, int L)
{
    int i = blockIdx.x * 256 + threadIdx.x;
    int e = i % D_INNER;
    int t = i / D_INNER;
    int l = t % L;
    float acc = cb[e];
#pragma unroll
    for (int j = 0; j < 4; j++) {
        int li = l - 3 + j;
        if (li >= 0) acc = fmaf(xz[(size_t)(t + li - l) * 1024 + e], cw[e * 4 + j], acc);
    }
    xc[i] = silu_f(acc);
}

// ---------------------------------------------------------------------------
// Selective scan + skip + gate.  One thread per (bn, channel e).
// ---------------------------------------------------------------------------
__global__ __launch_bounds__(256)
void scan_gate(float* __restrict__ dty,
               const float* __restrict__ xc,
               const float* __restrict__ xz,
               const float* __restrict__ dbl,
               const float* __restrict__ A_log,
               const float* __restrict__ Dvec,
               int L)
{
    int bn = blockIdx.x >> 1;
    int e  = ((blockIdx.x & 1) << 8) + threadIdx.x;

    float Ae[D_STATE], h[D_STATE];
#pragma unroll
    for (int s = 0; s < D_STATE; s++) {
        Ae[s] = -__expf(A_log[e * D_STATE + s]);
        h[s]  = 0.0f;
    }
    const float De = Dvec[e];

    for (int l = 0; l < L; l++) {
        int tk = bn * L + l;
        float dtv = dty[(size_t)tk * 512 + e];
        float u   = xc [(size_t)tk * 512 + e];
        float zv  = xz [(size_t)tk * 1024 + 512 + e];
        const float* bc = dbl + (size_t)tk * 48;
        float y = 0.0f;
#pragma unroll
        for (int s = 0; s < D_STATE; s++) {
            float dA = __expf(dtv * Ae[s]);
            h[s] = fmaf(dA, h[s], dtv * bc[16 + s] * u);
            y    = fmaf(h[s], bc[32 + s], y);
        }
        dty[(size_t)tk * 512 + e] = (y + u * De) * silu_f(zv);
    }
}

// ---------------------------------------------------------------------------
// One mamba stage.
// ---------------------------------------------------------------------------
template<int OUTMODE>
static void run_stage(const float* xin,
                      const float* in_w, const float* conv_w, const float* conv_b,
                      const float* xproj_w, const float* dt_w, const float* dt_b,
                      const float* A_log, const float* Dvec, const float* out_w,
                      float* xz, float* xc, float* dbl, float* dty, float* outp,
                      int Bn, int L, hipStream_t stream)
{
    const int M = TOKENS;
    // in_proj: [M,1024] = x[M,256] * in_w^T   (BN=256, grid 384x4)
    gemm_v2<256, 256, 0><<<dim3(M / 32, 1024 / 256), 256, 0, stream>>>(xin, in_w, xz, 1024);
    // conv + silu
    conv_silu<<<dim3((M * D_INNER) / 256), 256, 0, stream>>>(xz, conv_w, conv_b, xc, L);
    // x_proj: [M,48] = xc[M,512] * xproj_w^T  (384 blocks)
    gemm_nt<32,64,32,2,4,0><<<dim3(M / 32, 1), 256, 0, stream>>>(
        xc, 512, xproj_w, dbl, nullptr, M, 48, 512);
    // dt_proj + softplus
    gemm_nt<128,64,16,8,4,1><<<dim3(M / 128, 512 / 64), 256, 0, stream>>>(
        dbl, 48, dt_w, dty, dt_b, M, 512, 16);
    // scan + skip + gate
    scan_gate<<<dim3(Bn * 2), 256, 0, stream>>>(dty, xc, xz, dbl, A_log, Dvec, L);
    // out_proj with fused layout transpose (BN=128, grid 384x2 = 768 blocks)
    gemm_v2<512, 128, OUTMODE><<<dim3(M / 32, 256 / 128), 256, 0, stream>>>(dty, out_w, outp, 256);
}

extern "C" void kernel_launch(void* const* d_in, const int* in_sizes, int n_in,
                              void* d_out, int out_size, void* d_ws, size_t ws_size,
                              hipStream_t stream)
{
    const float* x = (const float*)d_in[0];
    const float* t_in_w    = (const float*)d_in[1];
    const float* t_conv_w  = (const float*)d_in[2];
    const float* t_conv_b  = (const float*)d_in[3];
    const float* t_xproj_w = (const float*)d_in[4];
    const float* t_dt_w    = (const float*)d_in[5];
    const float* t_dt_b    = (const float*)d_in[6];
    const float* t_A_log   = (const float*)d_in[7];
    const float* t_D       = (const float*)d_in[8];
    const float* t_out_w   = (const float*)d_in[9];
    const float* d_in_w    = (const float*)d_in[10];
    const float* d_conv_w  = (const float*)d_in[11];
    const float* d_conv_b  = (const float*)d_in[12];
    const float* d_xproj_w = (const float*)d_in[13];
    const float* d_dt_w    = (const float*)d_in[14];
    const float* d_dt_b    = (const float*)d_in[15];
    const float* d_A_log   = (const float*)d_in[16];
    const float* d_D       = (const float*)d_in[17];
    const float* d_out_w   = (const float*)d_in[18];

    float* ws  = (float*)d_ws;
    float* xz  = ws;
    float* xc  = xz  + (size_t)TOKENS * 1024;
    float* dbl = xc  + (size_t)TOKENS * 512;
    float* dty = dbl + (size_t)TOKENS * 48;
    float* xt  = dty + (size_t)TOKENS * 512;
    const size_t need_bytes = ((size_t)TOKENS * (1024 + 512 + 48 + 512 + 256)) * 4;
    if (ws_size < need_bytes) return;

    // stage 1: time scan, Bn = 128, L = 96
    run_stage<2>(x, t_in_w, t_conv_w, t_conv_b, t_xproj_w, t_dt_w, t_dt_b,
                 t_A_log, t_D, t_out_w, xz, xc, dbl, dty, xt,
                 NB * NVAR, SEG, stream);
    // stage 2: dimension scan, Bn = 384, L = 32
    run_stage<3>(xt, d_in_w, d_conv_w, d_conv_b, d_xproj_w, d_dt_w, d_dt_b,
                 d_A_log, d_D, d_out_w, xz, xc, dbl, dty, (float*)d_out,
                 NB * SEG, NVAR, stream);
}